// Round 2
// baseline (424.803 us; speedup 1.0000x reference)
//
#include <hip/hip_runtime.h>

// Lorenz RK4, B=16384 trajectories, NT=2000, dt=0.01.
// out[b*6003 + d*2001 + t], t=0 is x0.
//
// Round-2 design:
//  - 64 threads/block (1 wave), K=2 trajectories per lane as float2
//    ext-vectors -> v_pk_fma_f32 candidates (issue-free 2nd trajectory).
//  - Explicit fma (reference op order preserved; contraction is OURS).
//  - Double-buffered LDS time-tiles (TT=32): flush tile k-1 interleaved
//    into tile k's compute loop (4 rows/step), hiding LDS/store latency
//    under the RK4 dependency chain.

#define NT     2000
#define TT     32
#define NFULL  62          // 62 full 32-step tiles, then 16-step tail
#define TAIL   16
#define TROWS  2001
#define ROWS   128         // trajectories per block (64 lanes * K=2)
#define LROWS  129         // +1 pad -> all LDS access <= 2-way

typedef float v2f __attribute__((ext_vector_type(2)));
#define F2(a, b, c) __builtin_elementwise_fma((a), (b), (c))

__global__ __launch_bounds__(64) void lorenz_rk4(
    const float* __restrict__ x0,
    const float* __restrict__ p,
    float* __restrict__ out)
{
#pragma clang fp contract(off)
    __shared__ float buf[2][3][TT][LROWS];

    const int lane = threadIdx.x;
    const int b0   = blockIdx.x * ROWS;
    const int bA   = b0 + lane;          // trajectory in lane slot 0
    const int bB   = b0 + 64 + lane;     // trajectory in lane slot 1

    const float p0 = p[0], p1 = p[1], p2 = p[2];
    const v2f P0  = {p0, p0};
    const v2f P1  = {p1, p1};
    const v2f NP2 = {-p2, -p2};

    const float h1s = 0.01f;
    const float h2s = 0.01f / 2.0f;      // exact fp32 halving
    const float h6s = 0.01f / 6.0f;      // fp32-rounded, == jnp dt/6
    const v2f H1  = {h1s, h1s};
    const v2f H2  = {h2s, h2s};
    const v2f H6  = {h6s, h6s};
    const v2f TWO = {2.0f, 2.0f};

    v2f X = {x0[3*bA + 0], x0[3*bB + 0]};
    v2f Y = {x0[3*bA + 1], x0[3*bB + 1]};
    v2f Z = {x0[3*bA + 2], x0[3*bB + 2]};

    // t = 0 output
    {
        size_t gA = (size_t)bA * (3 * TROWS);
        size_t gB = (size_t)bB * (3 * TROWS);
        out[gA] = X[0]; out[gA + TROWS] = Y[0]; out[gA + 2*TROWS] = Z[0];
        out[gB] = X[1]; out[gB + TROWS] = Y[1]; out[gB + 2*TROWS] = Z[1];
    }

    // One RK4 step for both lane-trajectories; stage result in LDS tile CB.
#define STEP(CB, TL) do {                                                   \
        v2f k1x = P0 * (Y - X);                                             \
        v2f k1y = F2(X, P1 - Z, -Y);                                        \
        v2f k1z = F2(NP2, Z, X * Y);                                        \
        v2f ax = F2(H2, k1x, X), ay = F2(H2, k1y, Y), az = F2(H2, k1z, Z);  \
        v2f k2x = P0 * (ay - ax);                                           \
        v2f k2y = F2(ax, P1 - az, -ay);                                     \
        v2f k2z = F2(NP2, az, ax * ay);                                     \
        v2f bx = F2(H2, k2x, X), by = F2(H2, k2y, Y), bz = F2(H2, k2z, Z);  \
        v2f k3x = P0 * (by - bx);                                           \
        v2f k3y = F2(bx, P1 - bz, -by);                                     \
        v2f k3z = F2(NP2, bz, bx * by);                                     \
        v2f cx = F2(H1, k3x, X), cy = F2(H1, k3y, Y), cz = F2(H1, k3z, Z);  \
        v2f k4x = P0 * (cy - cx);                                           \
        v2f k4y = F2(cx, P1 - cz, -cy);                                     \
        v2f k4z = F2(NP2, cz, cx * cy);                                     \
        v2f sx = F2(TWO, k2x, k1x); sx = F2(TWO, k3x, sx); sx = sx + k4x;   \
        v2f sy = F2(TWO, k2y, k1y); sy = F2(TWO, k3y, sy); sy = sy + k4y;   \
        v2f sz = F2(TWO, k2z, k1z); sz = F2(TWO, k3z, sz); sz = sz + k4z;   \
        X = F2(H6, sx, X); Y = F2(H6, sy, Y); Z = F2(H6, sz, Z);            \
        buf[CB][0][TL][lane] = X[0]; buf[CB][0][TL][lane + 64] = X[1];      \
        buf[CB][1][TL][lane] = Y[0]; buf[CB][1][TL][lane + 64] = Y[1];      \
        buf[CB][2][TL][lane] = Z[0]; buf[CB][2][TL][lane + 64] = Z[1];      \
    } while (0)

    // Flush rows 2*RP, 2*RP+1 of tile FB (time base TB): half-wave per row,
    // lane&31 = time index -> 128B-contiguous stores per half-wave.
#define FLUSH_PAIR(FB, TB, RP) do {                                         \
        int rloc = 2*(RP) + (lane >> 5);                                    \
        int tloc = lane & 31;                                               \
        size_t g = (size_t)(b0 + rloc) * (3 * TROWS) + 1 + (TB) + tloc;     \
        out[g]             = buf[FB][0][tloc][rloc];                        \
        out[g +     TROWS] = buf[FB][1][tloc][rloc];                        \
        out[g + 2 * TROWS] = buf[FB][2][tloc][rloc];                        \
    } while (0)

    // Phase A: tile 0 -> buf 0, nothing to flush yet.
    for (int tl = 0; tl < TT; ++tl) {
        STEP(0, tl);
    }

    // Phase B: tiles 1..61 -> buf k&1, flush tile k-1 (4 rows per step).
    for (int k = 1; k < NFULL; ++k) {
        const int cb = k & 1;
        const int fb = cb ^ 1;
        const int tb = (k - 1) * TT;
        for (int tl = 0; tl < TT; ++tl) {
            STEP(cb, tl);
            FLUSH_PAIR(fb, tb, 2*tl);
            FLUSH_PAIR(fb, tb, 2*tl + 1);
        }
    }

    // Phase C: 16-step tail -> buf 0 (tile 62), flush tile 61 (buf 1, 8 rows/step).
    for (int tl = 0; tl < TAIL; ++tl) {
        STEP(0, tl);
        FLUSH_PAIR(1, (NFULL - 1) * TT, 4*tl);
        FLUSH_PAIR(1, (NFULL - 1) * TT, 4*tl + 1);
        FLUSH_PAIR(1, (NFULL - 1) * TT, 4*tl + 2);
        FLUSH_PAIR(1, (NFULL - 1) * TT, 4*tl + 3);
    }

    // Phase D: flush the tail tile (buf 0, 16 valid times, 4 rows/instr).
    for (int rp = 0; rp < 32; ++rp) {
        int rloc = 4*rp + (lane >> 4);
        int tloc = lane & 15;
        size_t g = (size_t)(b0 + rloc) * (3 * TROWS) + 1 + NFULL * TT + tloc;
        out[g]             = buf[0][0][tloc][rloc];
        out[g +     TROWS] = buf[0][1][tloc][rloc];
        out[g + 2 * TROWS] = buf[0][2][tloc][rloc];
    }

#undef STEP
#undef FLUSH_PAIR
}

extern "C" void kernel_launch(void* const* d_in, const int* in_sizes, int n_in,
                              void* d_out, int out_size, void* d_ws, size_t ws_size,
                              hipStream_t stream)
{
    const float* x0  = (const float*)d_in[0];
    const float* p   = (const float*)d_in[1];
    float*       out = (float*)d_out;

    const int B = in_sizes[0] / 3;      // 16384
    const int nblocks = B / ROWS;       // 128

    lorenz_rk4<<<nblocks, 64, 0, stream>>>(x0, p, out);
}

// Round 3
// 171.150 us; speedup vs baseline: 2.4821x; 2.4821x over previous
//
#include <hip/hip_runtime.h>

// Lorenz RK4, B=16384, NT=2000, dt=0.01. out[b*6003 + d*2001 + t].
//
// Round-3: producer/consumer wave split.
//  - 256 blocks x 128 threads (2 waves). Wave 0 computes 64 trajectories
//    (1/lane, state in registers), writes states to LDS only (no waits).
//  - Wave 1 drains the finished LDS tile to HBM with coalesced stores,
//    overlapped with wave 0 computing the next tile (double buffer).
//  - Barrier pairing: compute barrier #k = "tile k ready"; writer flushes
//    tile k between barriers #k and #k+1, so compute reuses the buffer
//    (tile k+2) only after the flush completed.
//  - Math identical to round 2 (explicit FMA, reference op order): absmax
//    was 0.0078 (10x under threshold), proven safe.

#define NT     2000
#define TT     32
#define NFULL  62          // 62 full tiles of 32 steps
#define TAIL   16          // + 16-step tail
#define TROWS  2001
#define ROWS   64          // trajectories per block
#define LROWS  65          // pad -> <=2-way LDS banking everywhere

#define FMA(a,b,c) __builtin_fmaf((a),(b),(c))

__global__ __launch_bounds__(128) void lorenz_rk4(
    const float* __restrict__ x0,
    const float* __restrict__ p,
    float* __restrict__ out)
{
#pragma clang fp contract(off)
    __shared__ float buf[2][3][TT][LROWS];   // 49.9 KB

    const int tid  = threadIdx.x;
    const int lane = tid & 63;
    const int b0   = blockIdx.x * ROWS;

    if (tid < 64) {
        // ================= compute wave =================
        const float p0  = p[0], p1 = p[1], p2n = -p[2];
        const float h1 = 0.01f;
        const float h2 = 0.01f / 2.0f;
        const float h6 = 0.01f / 6.0f;
        const int b = b0 + lane;
        float x = x0[3*b + 0], y = x0[3*b + 1], z = x0[3*b + 2];

        {   // t = 0 column
            size_t g = (size_t)b * (3 * TROWS);
            out[g] = x; out[g + TROWS] = y; out[g + 2*TROWS] = z;
        }

#define STEP() do {                                                          \
        float k1x = p0 * (y - x);                                            \
        float k1y = FMA(x, p1 - z, -y);                                      \
        float k1z = FMA(p2n, z, x * y);                                      \
        float ax = FMA(h2,k1x,x), ay = FMA(h2,k1y,y), az = FMA(h2,k1z,z);    \
        float k2x = p0 * (ay - ax);                                          \
        float k2y = FMA(ax, p1 - az, -ay);                                   \
        float k2z = FMA(p2n, az, ax * ay);                                   \
        float bx = FMA(h2,k2x,x), by = FMA(h2,k2y,y), bz = FMA(h2,k2z,z);    \
        float k3x = p0 * (by - bx);                                          \
        float k3y = FMA(bx, p1 - bz, -by);                                   \
        float k3z = FMA(p2n, bz, bx * by);                                   \
        float cx = FMA(h1,k3x,x), cy = FMA(h1,k3y,y), cz = FMA(h1,k3z,z);    \
        float k4x = p0 * (cy - cx);                                          \
        float k4y = FMA(cx, p1 - cz, -cy);                                   \
        float k4z = FMA(p2n, cz, cx * cy);                                   \
        float sx = FMA(2.0f,k2x,k1x); sx = FMA(2.0f,k3x,sx); sx += k4x;      \
        float sy = FMA(2.0f,k2y,k1y); sy = FMA(2.0f,k3y,sy); sy += k4y;      \
        float sz = FMA(2.0f,k2z,k1z); sz = FMA(2.0f,k3z,sz); sz += k4z;      \
        x = FMA(h6,sx,x); y = FMA(h6,sy,y); z = FMA(h6,sz,z);                \
    } while (0)

        for (int k = 0; k < NFULL; ++k) {
            float* bb = &buf[k & 1][0][0][0];
#pragma unroll
            for (int tl = 0; tl < TT; ++tl) {
                STEP();
                // ds_write with immediate offsets (tl, plane are constants)
                bb[              tl*LROWS + lane] = x;
                bb[  TT*LROWS  + tl*LROWS + lane] = y;
                bb[2*TT*LROWS  + tl*LROWS + lane] = z;
            }
            __syncthreads();                  // barrier #k: tile k ready
        }
#pragma unroll
        for (int tl = 0; tl < TAIL; ++tl) {   // tail tile -> buf 0
            STEP();
            buf[0][0][tl][lane] = x;
            buf[0][1][tl][lane] = y;
            buf[0][2][tl][lane] = z;
        }
        __syncthreads();                      // barrier #62: tail ready
#undef STEP
    } else {
        // ================= writer wave =================
        for (int k = 0; k < NFULL; ++k) {
            __syncthreads();                  // wait: tile k ready
            const float* bb = &buf[k & 1][0][0][0];
            const int tloc = lane & 31;       // time within tile
            int rloc = lane >> 5;             // starting row (0 or 1)
            size_t g = (size_t)(b0 + rloc) * (3 * TROWS) + 1 + k * TT + tloc;
#pragma unroll 8
            for (int rp = 0; rp < 32; ++rp) { // 2 rows per iteration
                float vx = bb[              tloc*LROWS + rloc];
                float vy = bb[  TT*LROWS  + tloc*LROWS + rloc];
                float vz = bb[2*TT*LROWS  + tloc*LROWS + rloc];
                out[g]             = vx;
                out[g +     TROWS] = vy;
                out[g + 2 * TROWS] = vz;
                rloc += 2;
                g    += (size_t)2 * (3 * TROWS);
            }
        }
        __syncthreads();                      // wait: tail ready
        {
            const int tloc = lane & 15;
            int rloc = lane >> 4;
            size_t g = (size_t)(b0 + rloc) * (3 * TROWS) + 1 + NFULL * TT + tloc;
#pragma unroll 8
            for (int rp = 0; rp < 16; ++rp) { // 4 rows per iteration
                float vx = buf[0][0][tloc][rloc];
                float vy = buf[0][1][tloc][rloc];
                float vz = buf[0][2][tloc][rloc];
                out[g]             = vx;
                out[g +     TROWS] = vy;
                out[g + 2 * TROWS] = vz;
                rloc += 4;
                g    += (size_t)4 * (3 * TROWS);
            }
        }
    }
}

extern "C" void kernel_launch(void* const* d_in, const int* in_sizes, int n_in,
                              void* d_out, int out_size, void* d_ws, size_t ws_size,
                              hipStream_t stream)
{
    const float* x0  = (const float*)d_in[0];
    const float* p   = (const float*)d_in[1];
    float*       out = (float*)d_out;

    const int B = in_sizes[0] / 3;        // 16384
    const int nblocks = B / ROWS;         // 256

    lorenz_rk4<<<nblocks, 128, 0, stream>>>(x0, p, out);
}